// Round 4
// baseline (1967.414 us; speedup 1.0000x reference)
//
#include <hip/hip_runtime.h>
#include <hip/hip_bf16.h>

typedef __attribute__((ext_vector_type(8))) short short8;
typedef __attribute__((ext_vector_type(4))) float f32x4;

__device__ __forceinline__ unsigned short f2bf(float v) {
  union { float f; unsigned int u; } a; a.f = v;
  unsigned int r = a.u + 0x7fffu + ((a.u >> 16) & 1u);
  return (unsigned short)(r >> 16);
}
__device__ __forceinline__ float bf2f(unsigned short h) {
  union { float f; unsigned int u; } a; a.u = ((unsigned int)h) << 16;
  return a.f;
}

// ---------------------------------------------------------------------------
// K0: reorder prim_w [oc][ic][kh][kw] -> Awr[khkw][oc][ic] as bf16 hi/lo,
//     and zero the two routing accumulators (2048 floats, contiguous).
// ---------------------------------------------------------------------------
__global__ void k0_prep(const float* __restrict__ prim_w,
                        unsigned short* __restrict__ awr_hi,
                        unsigned short* __restrict__ awr_lo,
                        float* __restrict__ bacc)
{
  if (blockIdx.x == 576) {
    for (int i = threadIdx.x; i < 2048; i += 256) bacc[i] = 0.f;
    return;
  }
  const int gid  = blockIdx.x * 256 + threadIdx.x;   // < 147456 exactly
  const int khkw = gid >> 14;
  const int rem  = gid & 16383;
  const int oc   = rem >> 8, ic = rem & 255;
  const float w  = prim_w[(oc * 256 + ic) * 9 + khkw];
  const unsigned short hb = f2bf(w);
  awr_hi[gid] = hb;
  awr_lo[gid] = f2bf(w - bf2f(hb));
}

// ---------------------------------------------------------------------------
// K1: fused conv1(relu) + primary-caps conv (split-bf16 MFMA GEMM) + squash.
// Block = 256 thr = 4 waves, wave w handles image blockIdx*4+w end-to-end.
// x^T tile in LDS: per image 65 rows (64 spatial + 1 zero row) x 256B
// (row = [hi: 64 ic x 2B | lo: 64 ic x 2B], byte offsets XOR'd by (row&15)<<4).
// GEMM: out[64 oc][64 sp], K = 9(khkw) x 256(ic), MFMA 16x16x32 bf16,
// 3-product hi/lo split. A-frags straight from global (L2-resident Awr).
// ---------------------------------------------------------------------------
__global__ __launch_bounds__(256, 2) void k1_convs(
    const float* __restrict__ data, const float* __restrict__ conv1_w,
    const float* __restrict__ conv1_b, const float* __restrict__ prim_b,
    const unsigned short* __restrict__ awr_hi,
    const unsigned short* __restrict__ awr_lo,
    float* __restrict__ u_out)
{
  __shared__ char  xsh[4][65 * 256];
  __shared__ float dpad[4][100];
  const int wv = threadIdx.x >> 6;
  const int ln = threadIdx.x & 63;
  const int b  = blockIdx.x * 4 + wv;
  char*  xs = xsh[wv];
  float* dp = dpad[wv];

  for (int i = ln; i < 100; i += 64) dp[i] = 0.f;      // zero-padded 10x10 input
  ((float*)(xs + 64 * 256))[ln] = 0.f;                 // zero row (invalid taps)
  {
    const float d = data[b * 64 + ln];
    dp[((ln >> 3) + 1) * 10 + (ln & 7) + 1] = d;
  }
  __syncthreads();

  const f32x4 vzero = {0.f, 0.f, 0.f, 0.f};
  f32x4 acc[4][4];
  #pragma unroll
  for (int i = 0; i < 4; ++i)
    #pragma unroll
    for (int j = 0; j < 4; ++j) acc[i][j] = vzero;

  const int lhi = ln >> 4;   // k-group 0..3
  const int llo = ln & 15;   // row/col within tile

  for (int c = 0; c < 4; ++c) {          // 64-ic chunks
    // ---- conv1 for ic = c*64 + ln, write split-bf16 x^T rows ----
    {
      const int ic = c * 64 + ln;
      float wc[9];
      #pragma unroll
      for (int k = 0; k < 9; ++k) wc[k] = conv1_w[ic * 9 + k];
      const float bc = conv1_b[ic];
      for (int sp = 0; sp < 64; ++sp) {
        const int h = sp >> 3, w = sp & 7;
        float v = bc;
        #pragma unroll
        for (int kh = 0; kh < 3; ++kh)
          #pragma unroll
          for (int kw = 0; kw < 3; ++kw)
            v += wc[kh * 3 + kw] * dp[(h + kh) * 10 + (w + kw)];
        v = fmaxf(v, 0.f);
        const unsigned short hb = f2bf(v);
        const unsigned short lb = f2bf(v - bf2f(hb));
        const int swz = (sp & 15) << 4;
        *(unsigned short*)(xs + sp * 256 + ((ln * 2) ^ swz))         = hb;
        *(unsigned short*)(xs + sp * 256 + (((ln * 2) | 128) ^ swz)) = lb;
      }
    }
    __syncthreads();

    // ---- MFMA GEMM over this chunk ----
    #pragma unroll
    for (int khkw = 0; khkw < 9; ++khkw) {
      const int dh = khkw / 3 - 1, dw = khkw % 3 - 1;
      int bbase[4], bswz[4];
      #pragma unroll
      for (int st = 0; st < 4; ++st) {
        const int sp = st * 16 + llo;
        const int hh = (sp >> 3) + dh, ww = (sp & 7) + dw;
        const bool ok = ((unsigned)hh < 8u) && ((unsigned)ww < 8u);
        const int row = ok ? (hh * 8 + ww) : 64;
        bbase[st] = row * 256;
        bswz[st]  = (row & 15) << 4;
      }
      const unsigned short* ah_p = awr_hi + khkw * 16384 + llo * 256 + c * 64 + lhi * 8;
      const unsigned short* al_p = awr_lo + khkw * 16384 + llo * 256 + c * 64 + lhi * 8;
      #pragma unroll
      for (int icb = 0; icb < 64; icb += 32) {
        short8 ah[4], al[4], bh[4], bl[4];
        #pragma unroll
        for (int ot = 0; ot < 4; ++ot) {
          ah[ot] = *(const short8*)(ah_p + ot * 4096 + icb);
          al[ot] = *(const short8*)(al_p + ot * 4096 + icb);
        }
        const int kb = icb * 2 + lhi * 16;
        #pragma unroll
        for (int st = 0; st < 4; ++st) {
          const char* p = xs + bbase[st];
          bh[st] = *(const short8*)(p + ((kb) ^ bswz[st]));
          bl[st] = *(const short8*)(p + ((kb | 128) ^ bswz[st]));
        }
        #pragma unroll
        for (int ot = 0; ot < 4; ++ot)
          #pragma unroll
          for (int st = 0; st < 4; ++st) {
            acc[ot][st] = __builtin_amdgcn_mfma_f32_16x16x32_bf16(ah[ot], bh[st], acc[ot][st], 0, 0, 0);
            acc[ot][st] = __builtin_amdgcn_mfma_f32_16x16x32_bf16(ah[ot], bl[st], acc[ot][st], 0, 0, 0);
            acc[ot][st] = __builtin_amdgcn_mfma_f32_16x16x32_bf16(al[ot], bh[st], acc[ot][st], 0, 0, 0);
          }
      }
    }
    __syncthreads();
  }

  // ---- bias + squash (over the 8 w's of each (oc,h)) + write u ----
  // D layout: row oc = ot*16 + (ln>>4)*4 + q ; col sp = st*16 + (ln&15).
  const int ub = b * 4096;
  #pragma unroll
  for (int ot = 0; ot < 4; ++ot) {
    #pragma unroll
    for (int q = 0; q < 4; ++q) {
      const int oc = ot * 16 + (lhi << 2) + q;
      const float bias = prim_b[oc];
      #pragma unroll
      for (int st = 0; st < 4; ++st) {
        float v  = acc[ot][st][q] + bias;
        float sq = v * v;
        sq += __shfl_xor(sq, 1);
        sq += __shfl_xor(sq, 2);
        sq += __shfl_xor(sq, 4);
        const float scale = sq / ((1.f + sq) * sqrtf(sq + 1e-9f));
        u_out[ub + oc * 64 + st * 16 + llo] = v * scale;
      }
    }
  }
}

// ---------------------------------------------------------------------------
// K2: one routing iteration. mode 0: uniform c, agreement -> bacc1.
//     mode 1: c=softmax(bacc1/B), agreement -> bacc2.
//     mode 2: c=softmax((bacc1+bacc2)/B), write v_j, masked, h0.
// Block = 512 thr, 16 batch rows; thread = (b_l = t>>5, o = (t>>4)&1,
// d-pair d0 = (t&15)*2). u_hat recomputed on the fly from u and W_digit.
// ---------------------------------------------------------------------------
#define K2_STAGE(R0)                                                          \
  do {                                                                        \
    int j = t;                                                                \
    u_s[j] = u[b0u + ((j >> 6) * 4096) + (R0) * 8 + (((j >> 3) & 7) * 8) + (j & 7)]; \
    j = t + 512;                                                              \
    u_s[j] = u[b0u + ((j >> 6) * 4096) + (R0) * 8 + (((j >> 3) & 7) * 8) + (j & 7)]; \
    _Pragma("unroll")                                                         \
    for (int k = 0; k < 8; ++k) w_s[k][t] = Wd[((R0) + k) * 512 + t];         \
  } while (0)

__global__ __launch_bounds__(512, 2) void k2_route(
    const float* __restrict__ u, const float* __restrict__ Wd,
    float* __restrict__ bacc1, float* __restrict__ bacc2,
    float* __restrict__ out, float* __restrict__ h0, const int mode)
{
  __shared__ float u_s[1024];       // [16 b][8 r][8 i]
  __shared__ float w_s[8][512];     // [8 r][o*256 + d*8 + i]
  __shared__ float c_s[512][2];
  __shared__ float bacc_s[1024];
  __shared__ float red_s[8][2];
  const int t   = threadIdx.x;
  const int b_l = t >> 5;
  const int q   = t & 31;
  const int o   = q >> 4;
  const int d0  = (q & 15) << 1;
  const int b   = blockIdx.x * 16 + b_l;
  const int b0u = blockIdx.x * 16 * 4096;

  if (mode != 0) {                                   // c = softmax over r
    const int r = t;
    float bv0 = bacc1[r * 2]     * (1.f / 4096.f);
    float bv1 = bacc1[r * 2 + 1] * (1.f / 4096.f);
    if (mode == 2) {
      bv0 += bacc2[r * 2]     * (1.f / 4096.f);
      bv1 += bacc2[r * 2 + 1] * (1.f / 4096.f);
    }
    float m0 = bv0, m1 = bv1;
    for (int s = 1; s < 64; s <<= 1) { m0 = fmaxf(m0, __shfl_xor(m0, s)); m1 = fmaxf(m1, __shfl_xor(m1, s)); }
    if ((t & 63) == 0) { red_s[t >> 6][0] = m0; red_s[t >> 6][1] = m1; }
    __syncthreads();
    m0 = red_s[0][0]; m1 = red_s[0][1];
    #pragma unroll
    for (int i = 1; i < 8; ++i) { m0 = fmaxf(m0, red_s[i][0]); m1 = fmaxf(m1, red_s[i][1]); }
    const float e0 = expf(bv0 - m0), e1 = expf(bv1 - m1);
    float s0 = e0, s1 = e1;
    for (int s = 1; s < 64; s <<= 1) { s0 += __shfl_xor(s0, s); s1 += __shfl_xor(s1, s); }
    __syncthreads();
    if ((t & 63) == 0) { red_s[t >> 6][0] = s0; red_s[t >> 6][1] = s1; }
    __syncthreads();
    s0 = 0.f; s1 = 0.f;
    #pragma unroll
    for (int i = 0; i < 8; ++i) { s0 += red_s[i][0]; s1 += red_s[i][1]; }
    c_s[r][0] = e0 / s0; c_s[r][1] = e1 / s1;
  }
  bacc_s[t] = 0.f; bacc_s[t + 512] = 0.f;

  // ---- pass 1: s_j = sum_r c[r,o] * (W[r,o,d,:] . u[b,r,:]) ----
  float sa0 = 0.f, sa1 = 0.f;
  for (int r0 = 0; r0 < 512; r0 += 8) {
    __syncthreads();
    K2_STAGE(r0);
    __syncthreads();
    #pragma unroll
    for (int rr = 0; rr < 8; ++rr) {
      const float* uu = &u_s[b_l * 64 + rr * 8];
      const float* w0 = &w_s[rr][o * 256 + d0 * 8];
      float uh0 = 0.f, uh1 = 0.f;
      #pragma unroll
      for (int i = 0; i < 8; ++i) { uh0 += w0[i] * uu[i]; uh1 += w0[8 + i] * uu[i]; }
      const float c = (mode == 0) ? (1.f / 512.f) : c_s[r0 + rr][o];
      sa0 += c * uh0; sa1 += c * uh1;
    }
  }
  // squash over 32 d (16 threads share (b,o))
  float sq = sa0 * sa0 + sa1 * sa1;
  sq += __shfl_xor(sq, 1); sq += __shfl_xor(sq, 2);
  sq += __shfl_xor(sq, 4); sq += __shfl_xor(sq, 8);
  const float scale = sq / ((1.f + sq) * sqrtf(sq + 1e-9f));
  const float v0 = sa0 * scale, v1 = sa1 * scale;

  if (mode < 2) {
    // ---- pass 2: agreement a = u_hat . v, sum over block's b, LDS acc ----
    for (int r0 = 0; r0 < 512; r0 += 8) {
      __syncthreads();
      K2_STAGE(r0);
      __syncthreads();
      #pragma unroll
      for (int rr = 0; rr < 8; ++rr) {
        const float* uu = &u_s[b_l * 64 + rr * 8];
        const float* w0 = &w_s[rr][o * 256 + d0 * 8];
        float uh0 = 0.f, uh1 = 0.f;
        #pragma unroll
        for (int i = 0; i < 8; ++i) { uh0 += w0[i] * uu[i]; uh1 += w0[8 + i] * uu[i]; }
        float ap = uh0 * v0 + uh1 * v1;
        ap += __shfl_xor(ap, 1); ap += __shfl_xor(ap, 2);
        ap += __shfl_xor(ap, 4); ap += __shfl_xor(ap, 8);
        ap += __shfl_xor(ap, 32);                    // + partner b in wave
        if (((t & 15) == 0) && ((t & 32) == 0))
          atomicAdd(&bacc_s[(r0 + rr) * 2 + o], ap);
      }
    }
    __syncthreads();
    float* bg = (mode == 0) ? bacc1 : bacc2;
    atomicAdd(&bg[t],       bacc_s[t]);
    atomicAdd(&bg[t + 512], bacc_s[t + 512]);
  } else {
    // ---- final: v_j out, masked, decoder input h0 ----
    out[b * 64 + o * 32 + d0]     = v0;
    out[b * 64 + o * 32 + d0 + 1] = v1;
    const float sqv = sq * scale * scale;            // ||v||^2 for own o
    const float sqo = __shfl_xor(sqv, 16);           // other o
    const bool win = (o == 0) ? !(sqo > sqv) : (sqv > sqo);  // np first-max
    if ((t & 15) == 0) out[524288 + b * 2 + o] = win ? 1.f : 0.f;
    h0[b * 64 + o * 32 + d0]     = win ? v0 : 0.f;
    h0[b * 64 + o * 32 + d0 + 1] = win ? v1 : 0.f;
  }
}

// ---------------------------------------------------------------------------
// K3: fused decoder: relu(h0 W1+b1) -> relu(W2+b2) -> sigmoid(W3+b3) -> rec.
// Block = 256 thr, 8 batch rows; h1/h2 staged in LDS.
// ---------------------------------------------------------------------------
__global__ __launch_bounds__(256, 2) void k3_dec(
    const float* __restrict__ h0,
    const float* __restrict__ W1, const float* __restrict__ b1,
    const float* __restrict__ W2, const float* __restrict__ b2,
    const float* __restrict__ W3, const float* __restrict__ b3,
    float* __restrict__ out)
{
  __shared__ float x_s[8][64];
  __shared__ float h1_s[8][512];
  __shared__ float h2_s[8][1024];
  const int t  = threadIdx.x;
  const int b0 = blockIdx.x * 8;
  ((float*)x_s)[t]       = h0[b0 * 64 + t];
  ((float*)x_s)[t + 256] = h0[b0 * 64 + 256 + t];
  __syncthreads();
  {
    const int j = t * 2;
    float a0[8], a1[8];
    #pragma unroll
    for (int i = 0; i < 8; ++i) { a0[i] = 0.f; a1[i] = 0.f; }
    for (int k = 0; k < 64; ++k) {
      const float w0 = W1[k * 512 + j], w1 = W1[k * 512 + j + 1];
      #pragma unroll
      for (int bb = 0; bb < 8; ++bb) {
        const float x = x_s[bb][k];
        a0[bb] += w0 * x; a1[bb] += w1 * x;
      }
    }
    const float c0 = b1[j], c1 = b1[j + 1];
    #pragma unroll
    for (int bb = 0; bb < 8; ++bb) {
      h1_s[bb][j]     = fmaxf(a0[bb] + c0, 0.f);
      h1_s[bb][j + 1] = fmaxf(a1[bb] + c1, 0.f);
    }
  }
  __syncthreads();
  {
    const int j = t * 4;
    float a[4][8];
    #pragma unroll
    for (int c = 0; c < 4; ++c)
      #pragma unroll
      for (int i = 0; i < 8; ++i) a[c][i] = 0.f;
    for (int k = 0; k < 512; ++k) {
      const f32x4 w = *(const f32x4*)(W2 + k * 1024 + j);
      #pragma unroll
      for (int bb = 0; bb < 8; ++bb) {
        const float x = h1_s[bb][k];
        #pragma unroll
        for (int c = 0; c < 4; ++c) a[c][bb] += w[c] * x;
      }
    }
    #pragma unroll
    for (int c = 0; c < 4; ++c) {
      const float bc = b2[j + c];
      #pragma unroll
      for (int bb = 0; bb < 8; ++bb)
        h2_s[bb][j + c] = fmaxf(a[c][bb] + bc, 0.f);
    }
  }
  __syncthreads();
  {
    const int j = t & 63, bq = t >> 6;
    float a0 = 0.f, a1 = 0.f;
    for (int k = 0; k < 1024; ++k) {
      const float w = W3[k * 64 + j];
      a0 += w * h2_s[bq * 2][k];
      a1 += w * h2_s[bq * 2 + 1][k];
    }
    const float bc = b3[j];
    out[262144 + (b0 + bq * 2) * 64 + j]     = 1.f / (1.f + expf(-(a0 + bc)));
    out[262144 + (b0 + bq * 2 + 1) * 64 + j] = 1.f / (1.f + expf(-(a1 + bc)));
  }
}

// ---------------------------------------------------------------------------
extern "C" void kernel_launch(void* const* d_in, const int* in_sizes, int n_in,
                              void* d_out, int out_size, void* d_ws, size_t ws_size,
                              hipStream_t stream) {
  (void)in_sizes; (void)n_in; (void)out_size; (void)ws_size;
  const float* data    = (const float*)d_in[0];
  const float* conv1_w = (const float*)d_in[1];
  const float* conv1_b = (const float*)d_in[2];
  const float* prim_w  = (const float*)d_in[3];
  const float* prim_b  = (const float*)d_in[4];
  const float* Wd      = (const float*)d_in[5];
  const float* dec1_w  = (const float*)d_in[6];
  const float* dec1_b  = (const float*)d_in[7];
  const float* dec2_w  = (const float*)d_in[8];
  const float* dec2_b  = (const float*)d_in[9];
  const float* dec3_w  = (const float*)d_in[10];
  const float* dec3_b  = (const float*)d_in[11];
  char* ws = (char*)d_ws;
  unsigned short* awr_hi = (unsigned short*)ws;                    // 294912 B
  unsigned short* awr_lo = (unsigned short*)(ws + 294912);         // 294912 B
  float* bacc1 = (float*)(ws + 589824);                            // 4096 B
  float* bacc2 = (float*)(ws + 593920);                            // 4096 B
  float* u     = (float*)(ws + 598016);                            // 67108864 B
  float* h0    = (float*)(ws + 598016 + 67108864);                 // 1048576 B
  float* out   = (float*)d_out;

  k0_prep<<<577, 256, 0, stream>>>(prim_w, awr_hi, awr_lo, bacc1); // zeros bacc1+bacc2
  k1_convs<<<1024, 256, 0, stream>>>(data, conv1_w, conv1_b, prim_b, awr_hi, awr_lo, u);
  k2_route<<<256, 512, 0, stream>>>(u, Wd, bacc1, bacc2, out, h0, 0);
  k2_route<<<256, 512, 0, stream>>>(u, Wd, bacc1, bacc2, out, h0, 1);
  k2_route<<<256, 512, 0, stream>>>(u, Wd, bacc1, bacc2, out, h0, 2);
  k3_dec<<<512, 256, 0, stream>>>(h0, dec1_w, dec1_b, dec2_w, dec2_b, dec3_w, dec3_b, out);
}

// Round 10
// 995.371 us; speedup vs baseline: 1.9766x; 1.9766x over previous
//
#include <hip/hip_runtime.h>
#include <hip/hip_bf16.h>

typedef __attribute__((ext_vector_type(8))) short short8;
typedef __attribute__((ext_vector_type(4))) float f32x4;

__device__ __forceinline__ unsigned short f2bf(float v) {
  union { float f; unsigned int u; } a; a.f = v;
  unsigned int r = a.u + 0x7fffu + ((a.u >> 16) & 1u);
  return (unsigned short)(r >> 16);
}
__device__ __forceinline__ float bf2f(unsigned short h) {
  union { float f; unsigned int u; } a; a.u = ((unsigned int)h) << 16;
  return a.f;
}

// ---------------------------------------------------------------------------
// K0: prim_w -> awr3 in FRAGMENT-ISSUE order (hi/lo split bf16), so each k1
// A-frag load is lane*16B fully coalesced. Flat idx = gid where
// gid = ((((khkw*4+c)*2+icb2)*4+ot)*64+ln)*8+j,
// oc = ot*16+(ln&15), ic = c*64+icb2*32+(ln>>4)*8+j.  Also zero blog (1024 f).
// ---------------------------------------------------------------------------
__global__ void k0_prep(const float* __restrict__ prim_w,
                        unsigned short* __restrict__ awr_hi,
                        unsigned short* __restrict__ awr_lo,
                        float* __restrict__ blog)
{
  if (blockIdx.x == 576) {
    for (int i = threadIdx.x; i < 1024; i += 256) blog[i] = 0.f;
    return;
  }
  const int gid  = blockIdx.x * 256 + threadIdx.x;   // < 147456
  const int j    = gid & 7;
  const int ln   = (gid >> 3) & 63;
  const int ot   = (gid >> 9) & 3;
  const int icb2 = (gid >> 11) & 1;
  const int c    = (gid >> 12) & 3;
  const int khkw = gid >> 14;
  const int oc = ot * 16 + (ln & 15);
  const int ic = c * 64 + icb2 * 32 + (ln >> 4) * 8 + j;
  const float w = prim_w[(oc * 256 + ic) * 9 + khkw];
  const unsigned short hb = f2bf(w);
  awr_hi[gid] = hb;
  awr_lo[gid] = f2bf(w - bf2f(hb));
}

// ---------------------------------------------------------------------------
// K1: fused conv1(relu) + primary-caps conv (split-bf16 MFMA) + squash.
// Same verified structure as r4 (absmax 6e-5) with two changes:
//  (a) A-frag loads now coalesced from awr3 (lane*16B), killing the 267 MB
//      gather leak;  (b) conv writes pack 2 ic per u32 (2 ic x 32 sp / lane).
// ---------------------------------------------------------------------------
__global__ __launch_bounds__(256, 2) void k1_convs(
    const float* __restrict__ data, const float* __restrict__ conv1_w,
    const float* __restrict__ conv1_b, const float* __restrict__ prim_b,
    const unsigned short* __restrict__ awr_hi,
    const unsigned short* __restrict__ awr_lo,
    float* __restrict__ u_out)
{
  __shared__ char  xsh[4][65 * 256];
  __shared__ float dpad[4][100];
  const int wv = threadIdx.x >> 6;
  const int ln = threadIdx.x & 63;
  const int b  = blockIdx.x * 4 + wv;
  char*  xs = xsh[wv];
  float* dp = dpad[wv];

  for (int i = ln; i < 100; i += 64) dp[i] = 0.f;
  ((float*)(xs + 64 * 256))[ln] = 0.f;                 // zero row (invalid taps)
  {
    const float d = data[b * 64 + ln];
    dp[((ln >> 3) + 1) * 10 + (ln & 7) + 1] = d;
  }
  __syncthreads();

  const f32x4 vzero = {0.f, 0.f, 0.f, 0.f};
  f32x4 acc[4][4];
  #pragma unroll
  for (int i = 0; i < 4; ++i)
    #pragma unroll
    for (int j = 0; j < 4; ++j) acc[i][j] = vzero;

  const int lhi = ln >> 4;
  const int llo = ln & 15;
  const int icp = ln & 31;         // ic pair: 2*icp, 2*icp+1
  const int sph = ln >> 5;         // sp half

  for (int c = 0; c < 4; ++c) {
    // ---- conv1: 2 ic x 32 sp per lane, packed u32 LDS writes ----
    {
      const int ic0 = c * 64 + 2 * icp;
      float wc0[9], wc1[9];
      #pragma unroll
      for (int k = 0; k < 9; ++k) { wc0[k] = conv1_w[ic0 * 9 + k]; wc1[k] = conv1_w[ic0 * 9 + 9 + k]; }
      const float bc0 = conv1_b[ic0], bc1 = conv1_b[ic0 + 1];
      for (int s = 0; s < 32; ++s) {
        const int sp = sph * 32 + s;
        const int h = sp >> 3, w = sp & 7;
        float v0 = bc0, v1 = bc1;
        #pragma unroll
        for (int kh = 0; kh < 3; ++kh)
          #pragma unroll
          for (int kw = 0; kw < 3; ++kw) {
            const float x = dp[(h + kh) * 10 + (w + kw)];
            v0 += wc0[kh * 3 + kw] * x;
            v1 += wc1[kh * 3 + kw] * x;
          }
        v0 = fmaxf(v0, 0.f); v1 = fmaxf(v1, 0.f);
        const unsigned short h0 = f2bf(v0), h1 = f2bf(v1);
        const unsigned short l0 = f2bf(v0 - bf2f(h0)), l1 = f2bf(v1 - bf2f(h1));
        const int swz = (sp & 15) << 4;
        *(unsigned int*)(xs + sp * 256 + ((4 * icp) ^ swz))         = (unsigned int)h0 | ((unsigned int)h1 << 16);
        *(unsigned int*)(xs + sp * 256 + (((4 * icp) | 128) ^ swz)) = (unsigned int)l0 | ((unsigned int)l1 << 16);
      }
    }
    __syncthreads();

    // ---- MFMA GEMM over this chunk ----
    #pragma unroll
    for (int khkw = 0; khkw < 9; ++khkw) {
      const int dh = khkw / 3 - 1, dw = khkw % 3 - 1;
      int bbase[4], bswz[4];
      #pragma unroll
      for (int st = 0; st < 4; ++st) {
        const int sp = st * 16 + llo;
        const int hh = (sp >> 3) + dh, ww = (sp & 7) + dw;
        const bool ok = ((unsigned)hh < 8u) && ((unsigned)ww < 8u);
        const int row = ok ? (hh * 8 + ww) : 64;
        bbase[st] = row * 256;
        bswz[st]  = (row & 15) << 4;
      }
      #pragma unroll
      for (int icb2 = 0; icb2 < 2; ++icb2) {
        const int abase = (((khkw * 4 + c) * 2 + icb2) * 4) * 512 + ln * 8;
        short8 ah[4], al[4], bh[4], bl[4];
        #pragma unroll
        for (int ot = 0; ot < 4; ++ot) {
          ah[ot] = *(const short8*)(awr_hi + abase + ot * 512);
          al[ot] = *(const short8*)(awr_lo + abase + ot * 512);
        }
        const int kb = icb2 * 64 + lhi * 16;
        #pragma unroll
        for (int st = 0; st < 4; ++st) {
          const char* p = xs + bbase[st];
          bh[st] = *(const short8*)(p + ((kb) ^ bswz[st]));
          bl[st] = *(const short8*)(p + ((kb | 128) ^ bswz[st]));
        }
        #pragma unroll
        for (int ot = 0; ot < 4; ++ot)
          #pragma unroll
          for (int st = 0; st < 4; ++st) {
            acc[ot][st] = __builtin_amdgcn_mfma_f32_16x16x32_bf16(ah[ot], bh[st], acc[ot][st], 0, 0, 0);
            acc[ot][st] = __builtin_amdgcn_mfma_f32_16x16x32_bf16(ah[ot], bl[st], acc[ot][st], 0, 0, 0);
            acc[ot][st] = __builtin_amdgcn_mfma_f32_16x16x32_bf16(al[ot], bh[st], acc[ot][st], 0, 0, 0);
          }
      }
    }
    __syncthreads();
  }

  // ---- bias + squash + write u ----
  const int ub = b * 4096;
  #pragma unroll
  for (int ot = 0; ot < 4; ++ot) {
    #pragma unroll
    for (int q = 0; q < 4; ++q) {
      const int oc = ot * 16 + (lhi << 2) + q;
      const float bias = prim_b[oc];
      #pragma unroll
      for (int st = 0; st < 4; ++st) {
        float v  = acc[ot][st][q] + bias;
        float sq = v * v;
        sq += __shfl_xor(sq, 1);
        sq += __shfl_xor(sq, 2);
        sq += __shfl_xor(sq, 4);
        const float scale = sq / ((1.f + sq) * sqrtf(sq + 1e-9f));
        u_out[ub + oc * 64 + st * 16 + llo] = v * scale;
      }
    }
  }
}

// ---------------------------------------------------------------------------
// CW kernel: c[r,o] (=1/512 in mode 0, else softmax over r of blog) then
// CW[od][ri] = c[r,o]*W[r,o,d,i]; also zeroes its slice of s.
// grid 64 x 256; block j owns ri in [j*64, j*64+64) i.e. r in [j*8, j*8+8).
// ---------------------------------------------------------------------------
__global__ __launch_bounds__(256, 2) void cw_kernel(
    const float* __restrict__ blog, const float* __restrict__ Wd,
    float* __restrict__ CW, float* __restrict__ s, const int mode)
{
  __shared__ float red[4][4];
  __shared__ float c_s[8][2];
  const int t  = threadIdx.x;
  const int r0 = blockIdx.x * 8;

  if (mode != 0) {
    const f32x4 bv = *(const f32x4*)&blog[t * 4];   // r=2t (o0,o1), r=2t+1 (o0,o1)
    float m0 = fmaxf(bv.x, bv.z), m1 = fmaxf(bv.y, bv.w);
    for (int sft = 1; sft < 64; sft <<= 1) { m0 = fmaxf(m0, __shfl_xor(m0, sft)); m1 = fmaxf(m1, __shfl_xor(m1, sft)); }
    if ((t & 63) == 0) { red[t >> 6][0] = m0; red[t >> 6][1] = m1; }
    __syncthreads();
    m0 = fmaxf(fmaxf(red[0][0], red[1][0]), fmaxf(red[2][0], red[3][0]));
    m1 = fmaxf(fmaxf(red[0][1], red[1][1]), fmaxf(red[2][1], red[3][1]));
    float s0 = expf(bv.x - m0) + expf(bv.z - m0);
    float s1 = expf(bv.y - m1) + expf(bv.w - m1);
    for (int sft = 1; sft < 64; sft <<= 1) { s0 += __shfl_xor(s0, sft); s1 += __shfl_xor(s1, sft); }
    __syncthreads();
    if ((t & 63) == 0) { red[t >> 6][2] = s0; red[t >> 6][3] = s1; }
    __syncthreads();
    s0 = red[0][2] + red[1][2] + red[2][2] + red[3][2];
    s1 = red[0][3] + red[1][3] + red[2][3] + red[3][3];
    if (t < 16) {
      const int rr = t >> 1, o = t & 1;
      const float m = o ? m1 : m0, dn = o ? s1 : s0;
      c_s[rr][o] = expf(blog[(r0 + rr) * 2 + o] - m) / dn;
    }
  } else {
    if (t < 16) c_s[t >> 1][t & 1] = 1.f / 512.f;
  }
  __syncthreads();

  // write CW slice: 16 elems/thread (one od row, 16 consecutive ri)
  const int od   = t >> 2;          // 0..63
  const int ril0 = (t & 3) * 16;
  const int o = od >> 5, d = od & 31;
  float* dst = CW + od * 4096 + r0 * 8 + ril0;
  #pragma unroll
  for (int q = 0; q < 16; ++q) {
    const int ril = ril0 + q;
    const int rr = ril >> 3, i = ril & 7;
    dst[q] = c_s[rr][o] * Wd[(((r0 + rr) * 2 + o) * 32 + d) * 8 + i];
  }
  // zero s slice
  f32x4* sz = (f32x4*)(s + blockIdx.x * 4096 + t * 16);
  const f32x4 z = {0.f, 0.f, 0.f, 0.f};
  sz[0] = z; sz[1] = z; sz[2] = z; sz[3] = z;
}

// ---------------------------------------------------------------------------
// SV GEMM: s[b,od] += sum_{ri in slice} u[b,ri]*CW[od,ri].
// grid 512 = bt(64) x ks(8); block tile 64b x 64od, K-slice 512 (8 chunks).
// thread: b = b0 + rg + 16i, od = cg + 16j (4x4 acc, 2-way-free LDS banks).
// ---------------------------------------------------------------------------
__global__ __launch_bounds__(256, 2) void sv_gemm(
    const float* __restrict__ u, const float* __restrict__ CW,
    float* __restrict__ s)
{
  __shared__ float u_s[64][68];
  __shared__ float w_s[64][68];
  const int t  = threadIdx.x;
  const int bt = blockIdx.x >> 3, ks = blockIdx.x & 7;
  const int b0 = bt * 64, k0 = ks * 512;
  const int cg = t & 15, rg = t >> 4;
  const int srow = t >> 2, scol = (t & 3) * 16;

  float acc[4][4];
  #pragma unroll
  for (int i = 0; i < 4; ++i)
    #pragma unroll
    for (int j = 0; j < 4; ++j) acc[i][j] = 0.f;

  for (int ch = 0; ch < 8; ++ch) {
    const int kb = k0 + ch * 64;
    const float* ug = u  + (b0 + srow) * 4096 + kb + scol;
    const float* wg = CW + srow * 4096 + kb + scol;
    #pragma unroll
    for (int q = 0; q < 4; ++q) {
      *(f32x4*)&u_s[srow][scol + q * 4] = *(const f32x4*)(ug + q * 4);
      *(f32x4*)&w_s[srow][scol + q * 4] = *(const f32x4*)(wg + q * 4);
    }
    __syncthreads();
    #pragma unroll 4
    for (int k4 = 0; k4 < 16; ++k4) {
      f32x4 uv[4], wv[4];
      #pragma unroll
      for (int i = 0; i < 4; ++i) uv[i] = *(const f32x4*)&u_s[rg + 16 * i][k4 * 4];
      #pragma unroll
      for (int j = 0; j < 4; ++j) wv[j] = *(const f32x4*)&w_s[cg + 16 * j][k4 * 4];
      #pragma unroll
      for (int i = 0; i < 4; ++i)
        #pragma unroll
        for (int j = 0; j < 4; ++j)
          acc[i][j] += uv[i].x * wv[j].x + uv[i].y * wv[j].y + uv[i].z * wv[j].z + uv[i].w * wv[j].w;
    }
    __syncthreads();
  }
  #pragma unroll
  for (int i = 0; i < 4; ++i)
    #pragma unroll
    for (int j = 0; j < 4; ++j)
      atomicAdd(&s[(b0 + rg + 16 * i) * 64 + cg + 16 * j], acc[i][j]);
}

// ---------------------------------------------------------------------------
// SQ kernel: v = squash(s) in-place; final: write out tuple pieces + h0;
// else zero G for the upcoming g_gemm.
// grid 256 x 256; b = blk*16 + t>>4, lane l = t&15 owns od = l*4..l*4+3.
// ---------------------------------------------------------------------------
__global__ __launch_bounds__(256, 2) void sq_kernel(
    float* __restrict__ s, float* __restrict__ G,
    float* __restrict__ out, float* __restrict__ h0, const int final_)
{
  const int t = threadIdx.x;
  const int b = blockIdx.x * 16 + (t >> 4);
  const int l = t & 15;
  const int o = l >> 3;
  f32x4 s4 = *(const f32x4*)&s[b * 64 + l * 4];
  float sq = s4.x * s4.x + s4.y * s4.y + s4.z * s4.z + s4.w * s4.w;
  sq += __shfl_xor(sq, 1); sq += __shfl_xor(sq, 2); sq += __shfl_xor(sq, 4);
  const float scale = sq / ((1.f + sq) * sqrtf(sq + 1e-9f));
  f32x4 v4;
  v4.x = s4.x * scale; v4.y = s4.y * scale; v4.z = s4.z * scale; v4.w = s4.w * scale;
  if (!final_) {
    *(f32x4*)&s[b * 64 + l * 4] = v4;                 // v in-place
    const f32x4 z = {0.f, 0.f, 0.f, 0.f};
    *(f32x4*)&G[blockIdx.x * 1024 + t * 4] = z;       // zero G
  } else {
    *(f32x4*)&out[b * 64 + l * 4] = v4;               // output v_j
    const float sqv = sq * scale * scale;             // ||v_o||^2
    const float sqo = __shfl_xor(sqv, 8);
    const bool win = (o == 0) ? !(sqo > sqv) : (sqv > sqo);   // np first-max
    if (l == 0 || l == 8) out[524288 + b * 2 + o] = win ? 1.f : 0.f;
    f32x4 hz = win ? v4 : f32x4{0.f, 0.f, 0.f, 0.f};
    *(f32x4*)&h0[b * 64 + l * 4] = hz;
  }
}

// ---------------------------------------------------------------------------
// G GEMM: G[od, ri] += sum_{b in slice} v[b,od]*u[b,ri].
// grid 512 = rt(64) x bs(8); tile 64od x 64ri, K-slice 512 b (8 chunks of 64).
// outer-product style: per b read v4 (od) + u4 (ri).
// ---------------------------------------------------------------------------
__global__ __launch_bounds__(256, 2) void g_gemm(
    const float* __restrict__ u, const float* __restrict__ v,
    float* __restrict__ G)
{
  __shared__ float v_s[64][68];
  __shared__ float q_s[64][68];
  const int t  = threadIdx.x;
  const int rt = blockIdx.x >> 3, bs = blockIdx.x & 7;
  const int ri0 = rt * 64, b0 = bs * 512;
  const int cg = t & 15, rg = t >> 4;    // od4 = rg*4 (broadcast rows), ri4 = cg*4
  const int srow = t >> 2, scol = (t & 3) * 16;

  float acc[4][4];
  #pragma unroll
  for (int i = 0; i < 4; ++i)
    #pragma unroll
    for (int j = 0; j < 4; ++j) acc[i][j] = 0.f;

  for (int ch = 0; ch < 8; ++ch) {
    const int bb = b0 + ch * 64;
    const float* vg = v + (bb + srow) * 64 + scol;
    const float* ug = u + (bb + srow) * 4096 + ri0 + scol;
    #pragma unroll
    for (int q = 0; q < 4; ++q) {
      *(f32x4*)&v_s[srow][scol + q * 4] = *(const f32x4*)(vg + q * 4);
      *(f32x4*)&q_s[srow][scol + q * 4] = *(const f32x4*)(ug + q * 4);
    }
    __syncthreads();
    #pragma unroll 4
    for (int k = 0; k < 64; ++k) {
      const f32x4 vv = *(const f32x4*)&v_s[k][rg * 4];
      const f32x4 uu = *(const f32x4*)&q_s[k][cg * 4];
      acc[0][0] += vv.x * uu.x; acc[0][1] += vv.x * uu.y; acc[0][2] += vv.x * uu.z; acc[0][3] += vv.x * uu.w;
      acc[1][0] += vv.y * uu.x; acc[1][1] += vv.y * uu.y; acc[1][2] += vv.y * uu.z; acc[1][3] += vv.y * uu.w;
      acc[2][0] += vv.z * uu.x; acc[2][1] += vv.z * uu.y; acc[2][2] += vv.z * uu.z; acc[2][3] += vv.z * uu.w;
      acc[3][0] += vv.w * uu.x; acc[3][1] += vv.w * uu.y; acc[3][2] += vv.w * uu.z; acc[3][3] += vv.w * uu.w;
    }
    __syncthreads();
  }
  #pragma unroll
  for (int i = 0; i < 4; ++i)
    #pragma unroll
    for (int j = 0; j < 4; ++j)
      atomicAdd(&G[(rg * 4 + i) * 4096 + ri0 + cg * 4 + j], acc[i][j]);
}

// ---------------------------------------------------------------------------
// BL kernel: blog[r,o] += (1/4096) * sum_{d,i} W[r,o,d,i] * G[o*32+d, r*8+i].
// grid 64 x 256; 16 threads per (r,o) pair, 16 terms each, shfl-reduce.
// ---------------------------------------------------------------------------
__global__ __launch_bounds__(256, 2) void bl_kernel(
    const float* __restrict__ Wd, const float* __restrict__ G,
    float* __restrict__ blog)
{
  const int t = threadIdx.x;
  const int p = t >> 4, l = t & 15;
  const int r = blockIdx.x * 8 + (p >> 1), o = p & 1;
  float sum = 0.f;
  #pragma unroll
  for (int q = 0; q < 16; ++q) {
    const int idx = l * 16 + q;
    const int d = idx >> 3, i = idx & 7;
    sum += Wd[((r * 2 + o) * 32 + d) * 8 + i] * G[(o * 32 + d) * 4096 + r * 8 + i];
  }
  sum += __shfl_xor(sum, 1); sum += __shfl_xor(sum, 2);
  sum += __shfl_xor(sum, 4); sum += __shfl_xor(sum, 8);
  if (l == 0) blog[r * 2 + o] += sum * (1.f / 4096.f);
}

// ---------------------------------------------------------------------------
// K3: fused decoder (unchanged from verified r4 version).
// ---------------------------------------------------------------------------
__global__ __launch_bounds__(256, 2) void k3_dec(
    const float* __restrict__ h0,
    const float* __restrict__ W1, const float* __restrict__ b1,
    const float* __restrict__ W2, const float* __restrict__ b2,
    const float* __restrict__ W3, const float* __restrict__ b3,
    float* __restrict__ out)
{
  __shared__ float x_s[8][64];
  __shared__ float h1_s[8][512];
  __shared__ float h2_s[8][1024];
  const int t  = threadIdx.x;
  const int b0 = blockIdx.x * 8;
  ((float*)x_s)[t]       = h0[b0 * 64 + t];
  ((float*)x_s)[t + 256] = h0[b0 * 64 + 256 + t];
  __syncthreads();
  {
    const int j = t * 2;
    float a0[8], a1[8];
    #pragma unroll
    for (int i = 0; i < 8; ++i) { a0[i] = 0.f; a1[i] = 0.f; }
    for (int k = 0; k < 64; ++k) {
      const float w0 = W1[k * 512 + j], w1 = W1[k * 512 + j + 1];
      #pragma unroll
      for (int bb = 0; bb < 8; ++bb) {
        const float x = x_s[bb][k];
        a0[bb] += w0 * x; a1[bb] += w1 * x;
      }
    }
    const float c0 = b1[j], c1 = b1[j + 1];
    #pragma unroll
    for (int bb = 0; bb < 8; ++bb) {
      h1_s[bb][j]     = fmaxf(a0[bb] + c0, 0.f);
      h1_s[bb][j + 1] = fmaxf(a1[bb] + c1, 0.f);
    }
  }
  __syncthreads();
  {
    const int j = t * 4;
    float a[4][8];
    #pragma unroll
    for (int c = 0; c < 4; ++c)
      #pragma unroll
      for (int i = 0; i < 8; ++i) a[c][i] = 0.f;
    for (int k = 0; k < 512; ++k) {
      const f32x4 w = *(const f32x4*)(W2 + k * 1024 + j);
      #pragma unroll
      for (int bb = 0; bb < 8; ++bb) {
        const float x = h1_s[bb][k];
        #pragma unroll
        for (int c = 0; c < 4; ++c) a[c][bb] += w[c] * x;
      }
    }
    #pragma unroll
    for (int c = 0; c < 4; ++c) {
      const float bc = b2[j + c];
      #pragma unroll
      for (int bb = 0; bb < 8; ++bb)
        h2_s[bb][j + c] = fmaxf(a[c][bb] + bc, 0.f);
    }
  }
  __syncthreads();
  {
    const int j = t & 63, bq = t >> 6;
    float a0 = 0.f, a1 = 0.f;
    for (int k = 0; k < 1024; ++k) {
      const float w = W3[k * 64 + j];
      a0 += w * h2_s[bq * 2][k];
      a1 += w * h2_s[bq * 2 + 1][k];
    }
    const float bc = b3[j];
    out[262144 + (b0 + bq * 2) * 64 + j]     = 1.f / (1.f + expf(-(a0 + bc)));
    out[262144 + (b0 + bq * 2 + 1) * 64 + j] = 1.f / (1.f + expf(-(a1 + bc)));
  }
}

// ---------------------------------------------------------------------------
extern "C" void kernel_launch(void* const* d_in, const int* in_sizes, int n_in,
                              void* d_out, int out_size, void* d_ws, size_t ws_size,
                              hipStream_t stream) {
  (void)in_sizes; (void)n_in; (void)out_size; (void)ws_size;
  const float* data    = (const float*)d_in[0];
  const float* conv1_w = (const float*)d_in[1];
  const float* conv1_b = (const float*)d_in[2];
  const float* prim_w  = (const float*)d_in[3];
  const float* prim_b  = (const float*)d_in[4];
  const float* Wd      = (const float*)d_in[5];
  const float* dec1_w  = (const float*)d_in[6];
  const float* dec1_b  = (const float*)d_in[7];
  const float* dec2_w  = (const float*)d_in[8];
  const float* dec2_b  = (const float*)d_in[9];
  const float* dec3_w  = (const float*)d_in[10];
  const float* dec3_b  = (const float*)d_in[11];
  char* ws = (char*)d_ws;
  unsigned short* awr_hi = (unsigned short*)ws;                    //   294912 B
  unsigned short* awr_lo = (unsigned short*)(ws + 294912);         //   294912 B
  float* blog = (float*)(ws + 589824);                             //     4096 B
  float* u    = (float*)(ws + 593920);                             // 67108864 B
  float* CW   = (float*)(ws + 593920 + 67108864);                  //  1048576 B
  float* s    = (float*)(ws + 593920 + 67108864 + 1048576);        //  1048576 B (v in-place)
  float* G    = (float*)(ws + 593920 + 67108864 + 2097152);        //  1048576 B
  float* h0   = CW;                                                //  alias: CW dead after last sv
  float* out  = (float*)d_out;

  k0_prep<<<577, 256, 0, stream>>>(prim_w, awr_hi, awr_lo, blog);
  k1_convs<<<1024, 256, 0, stream>>>(data, conv1_w, conv1_b, prim_b, awr_hi, awr_lo, u);
  // routing iteration 0 (uniform c)
  cw_kernel<<<64, 256, 0, stream>>>(blog, Wd, CW, s, 0);
  sv_gemm<<<512, 256, 0, stream>>>(u, CW, s);
  sq_kernel<<<256, 256, 0, stream>>>(s, G, out, h0, 0);
  g_gemm<<<512, 256, 0, stream>>>(u, s, G);
  bl_kernel<<<64, 256, 0, stream>>>(Wd, G, blog);
  // routing iteration 1
  cw_kernel<<<64, 256, 0, stream>>>(blog, Wd, CW, s, 1);
  sv_gemm<<<512, 256, 0, stream>>>(u, CW, s);
  sq_kernel<<<256, 256, 0, stream>>>(s, G, out, h0, 0);
  g_gemm<<<512, 256, 0, stream>>>(u, s, G);
  bl_kernel<<<64, 256, 0, stream>>>(Wd, G, blog);
  // routing iteration 2 (final)
  cw_kernel<<<64, 256, 0, stream>>>(blog, Wd, CW, s, 1);
  sv_gemm<<<512, 256, 0, stream>>>(u, CW, s);
  sq_kernel<<<256, 256, 0, stream>>>(s, G, out, h0, 1);
  // decoder
  k3_dec<<<512, 256, 0, stream>>>(h0, dec1_w, dec1_b, dec2_w, dec2_b, dec3_w, dec3_b, out);
}

// Round 11
// 985.906 us; speedup vs baseline: 1.9955x; 1.0096x over previous
//
#include <hip/hip_runtime.h>
#include <hip/hip_bf16.h>

typedef __attribute__((ext_vector_type(8))) short short8;
typedef __attribute__((ext_vector_type(4))) float f32x4;

__device__ __forceinline__ unsigned short f2bf(float v) {
  union { float f; unsigned int u; } a; a.f = v;
  unsigned int r = a.u + 0x7fffu + ((a.u >> 16) & 1u);
  return (unsigned short)(r >> 16);
}
__device__ __forceinline__ float bf2f(unsigned short h) {
  union { float f; unsigned int u; } a; a.u = ((unsigned int)h) << 16;
  return a.f;
}

// ---------------------------------------------------------------------------
// K0: prim_w -> awr3 in FRAGMENT-ISSUE order (hi/lo split bf16), so each k1
// A-frag load is lane*16B fully coalesced. Also zero blog (1024 f).
// ---------------------------------------------------------------------------
__global__ void k0_prep(const float* __restrict__ prim_w,
                        unsigned short* __restrict__ awr_hi,
                        unsigned short* __restrict__ awr_lo,
                        float* __restrict__ blog)
{
  if (blockIdx.x == 576) {
    for (int i = threadIdx.x; i < 1024; i += 256) blog[i] = 0.f;
    return;
  }
  const int gid  = blockIdx.x * 256 + threadIdx.x;   // < 147456
  const int j    = gid & 7;
  const int ln   = (gid >> 3) & 63;
  const int ot   = (gid >> 9) & 3;
  const int icb2 = (gid >> 11) & 1;
  const int c    = (gid >> 12) & 3;
  const int khkw = gid >> 14;
  const int oc = ot * 16 + (ln & 15);
  const int ic = c * 64 + icb2 * 32 + (ln >> 4) * 8 + j;
  const float w = prim_w[(oc * 256 + ic) * 9 + khkw];
  const unsigned short hb = f2bf(w);
  awr_hi[gid] = hb;
  awr_lo[gid] = f2bf(w - bf2f(hb));
}

// ---------------------------------------------------------------------------
// K1: fused conv1(relu) + primary-caps conv (split-bf16 MFMA) + squash.
// r10 change: epilogue stages the 64x64 output tile in LDS (reusing xs) and
// writes u with 16 fully-coalesced f32x4 stores (1KB/wave-instr, full lines)
// -- kills the partial-line RMW that made k1 HBM-bound (FETCH 227MB/WRITE
// 178MB for a 67MB output).
// ---------------------------------------------------------------------------
__global__ __launch_bounds__(256, 2) void k1_convs(
    const float* __restrict__ data, const float* __restrict__ conv1_w,
    const float* __restrict__ conv1_b, const float* __restrict__ prim_b,
    const unsigned short* __restrict__ awr_hi,
    const unsigned short* __restrict__ awr_lo,
    float* __restrict__ u_out)
{
  __shared__ char  xsh[4][65 * 256];
  __shared__ float dpad[4][100];
  const int wv = threadIdx.x >> 6;
  const int ln = threadIdx.x & 63;
  const int b  = blockIdx.x * 4 + wv;
  char*  xs = xsh[wv];
  float* dp = dpad[wv];

  for (int i = ln; i < 100; i += 64) dp[i] = 0.f;
  ((float*)(xs + 64 * 256))[ln] = 0.f;                 // zero row (invalid taps)
  {
    const float d = data[b * 64 + ln];
    dp[((ln >> 3) + 1) * 10 + (ln & 7) + 1] = d;
  }
  __syncthreads();

  const f32x4 vzero = {0.f, 0.f, 0.f, 0.f};
  f32x4 acc[4][4];
  #pragma unroll
  for (int i = 0; i < 4; ++i)
    #pragma unroll
    for (int j = 0; j < 4; ++j) acc[i][j] = vzero;

  const int lhi = ln >> 4;
  const int llo = ln & 15;
  const int icp = ln & 31;         // ic pair: 2*icp, 2*icp+1
  const int sph = ln >> 5;         // sp half

  for (int c = 0; c < 4; ++c) {
    // ---- conv1: 2 ic x 32 sp per lane, packed u32 LDS writes ----
    {
      const int ic0 = c * 64 + 2 * icp;
      float wc0[9], wc1[9];
      #pragma unroll
      for (int k = 0; k < 9; ++k) { wc0[k] = conv1_w[ic0 * 9 + k]; wc1[k] = conv1_w[ic0 * 9 + 9 + k]; }
      const float bc0 = conv1_b[ic0], bc1 = conv1_b[ic0 + 1];
      for (int s = 0; s < 32; ++s) {
        const int sp = sph * 32 + s;
        const int h = sp >> 3, w = sp & 7;
        float v0 = bc0, v1 = bc1;
        #pragma unroll
        for (int kh = 0; kh < 3; ++kh)
          #pragma unroll
          for (int kw = 0; kw < 3; ++kw) {
            const float x = dp[(h + kh) * 10 + (w + kw)];
            v0 += wc0[kh * 3 + kw] * x;
            v1 += wc1[kh * 3 + kw] * x;
          }
        v0 = fmaxf(v0, 0.f); v1 = fmaxf(v1, 0.f);
        const unsigned short h0 = f2bf(v0), h1 = f2bf(v1);
        const unsigned short l0 = f2bf(v0 - bf2f(h0)), l1 = f2bf(v1 - bf2f(h1));
        const int swz = (sp & 15) << 4;
        *(unsigned int*)(xs + sp * 256 + ((4 * icp) ^ swz))         = (unsigned int)h0 | ((unsigned int)h1 << 16);
        *(unsigned int*)(xs + sp * 256 + (((4 * icp) | 128) ^ swz)) = (unsigned int)l0 | ((unsigned int)l1 << 16);
      }
    }
    __syncthreads();

    // ---- MFMA GEMM over this chunk ----
    #pragma unroll
    for (int khkw = 0; khkw < 9; ++khkw) {
      const int dh = khkw / 3 - 1, dw = khkw % 3 - 1;
      int bbase[4], bswz[4];
      #pragma unroll
      for (int st = 0; st < 4; ++st) {
        const int sp = st * 16 + llo;
        const int hh = (sp >> 3) + dh, ww = (sp & 7) + dw;
        const bool ok = ((unsigned)hh < 8u) && ((unsigned)ww < 8u);
        const int row = ok ? (hh * 8 + ww) : 64;
        bbase[st] = row * 256;
        bswz[st]  = (row & 15) << 4;
      }
      #pragma unroll
      for (int icb2 = 0; icb2 < 2; ++icb2) {
        const int abase = (((khkw * 4 + c) * 2 + icb2) * 4) * 512 + ln * 8;
        short8 ah[4], al[4], bh[4], bl[4];
        #pragma unroll
        for (int ot = 0; ot < 4; ++ot) {
          ah[ot] = *(const short8*)(awr_hi + abase + ot * 512);
          al[ot] = *(const short8*)(awr_lo + abase + ot * 512);
        }
        const int kb = icb2 * 64 + lhi * 16;
        #pragma unroll
        for (int st = 0; st < 4; ++st) {
          const char* p = xs + bbase[st];
          bh[st] = *(const short8*)(p + ((kb) ^ bswz[st]));
          bl[st] = *(const short8*)(p + ((kb | 128) ^ bswz[st]));
        }
        #pragma unroll
        for (int ot = 0; ot < 4; ++ot)
          #pragma unroll
          for (int st = 0; st < 4; ++st) {
            acc[ot][st] = __builtin_amdgcn_mfma_f32_16x16x32_bf16(ah[ot], bh[st], acc[ot][st], 0, 0, 0);
            acc[ot][st] = __builtin_amdgcn_mfma_f32_16x16x32_bf16(ah[ot], bl[st], acc[ot][st], 0, 0, 0);
            acc[ot][st] = __builtin_amdgcn_mfma_f32_16x16x32_bf16(al[ot], bh[st], acc[ot][st], 0, 0, 0);
          }
      }
    }
    __syncthreads();
  }

  // ---- bias + squash -> LDS staging tile [64][64] f32 (reuses xs) ----
  float* xsf = (float*)xs;
  #pragma unroll
  for (int ot = 0; ot < 4; ++ot) {
    #pragma unroll
    for (int q = 0; q < 4; ++q) {
      const int oc = ot * 16 + (lhi << 2) + q;
      const float bias = prim_b[oc];
      #pragma unroll
      for (int st = 0; st < 4; ++st) {
        float v  = acc[ot][st][q] + bias;
        float sq = v * v;
        sq += __shfl_xor(sq, 1);
        sq += __shfl_xor(sq, 2);
        sq += __shfl_xor(sq, 4);
        const float scale = sq / ((1.f + sq) * sqrtf(sq + 1e-9f));
        xsf[oc * 64 + st * 16 + llo] = v * scale;
      }
    }
  }
  __syncthreads();
  // ---- coalesced u write: 16 x f32x4, 1KB contiguous per wave-instr ----
  const int ub = b * 4096;
  #pragma unroll
  for (int it = 0; it < 16; ++it) {
    const int f = it * 256 + ln * 4;
    *(f32x4*)&u_out[ub + f] = *(const f32x4*)&xsf[f];
  }
}

// ---------------------------------------------------------------------------
// CW kernel: c[r,o] (=1/512 in mode 0, else softmax over r of blog) then
// CW[od][ri] = c[r,o]*W[r,o,d,i]; also zeroes its slice of s.
// ---------------------------------------------------------------------------
__global__ __launch_bounds__(256, 2) void cw_kernel(
    const float* __restrict__ blog, const float* __restrict__ Wd,
    float* __restrict__ CW, float* __restrict__ s, const int mode)
{
  __shared__ float red[4][4];
  __shared__ float c_s[8][2];
  const int t  = threadIdx.x;
  const int r0 = blockIdx.x * 8;

  if (mode != 0) {
    const f32x4 bv = *(const f32x4*)&blog[t * 4];   // r=2t (o0,o1), r=2t+1 (o0,o1)
    float m0 = fmaxf(bv.x, bv.z), m1 = fmaxf(bv.y, bv.w);
    for (int sft = 1; sft < 64; sft <<= 1) { m0 = fmaxf(m0, __shfl_xor(m0, sft)); m1 = fmaxf(m1, __shfl_xor(m1, sft)); }
    if ((t & 63) == 0) { red[t >> 6][0] = m0; red[t >> 6][1] = m1; }
    __syncthreads();
    m0 = fmaxf(fmaxf(red[0][0], red[1][0]), fmaxf(red[2][0], red[3][0]));
    m1 = fmaxf(fmaxf(red[0][1], red[1][1]), fmaxf(red[2][1], red[3][1]));
    float s0 = expf(bv.x - m0) + expf(bv.z - m0);
    float s1 = expf(bv.y - m1) + expf(bv.w - m1);
    for (int sft = 1; sft < 64; sft <<= 1) { s0 += __shfl_xor(s0, sft); s1 += __shfl_xor(s1, sft); }
    __syncthreads();
    if ((t & 63) == 0) { red[t >> 6][2] = s0; red[t >> 6][3] = s1; }
    __syncthreads();
    s0 = red[0][2] + red[1][2] + red[2][2] + red[3][2];
    s1 = red[0][3] + red[1][3] + red[2][3] + red[3][3];
    if (t < 16) {
      const int rr = t >> 1, o = t & 1;
      const float m = o ? m1 : m0, dn = o ? s1 : s0;
      c_s[rr][o] = expf(blog[(r0 + rr) * 2 + o] - m) / dn;
    }
  } else {
    if (t < 16) c_s[t >> 1][t & 1] = 1.f / 512.f;
  }
  __syncthreads();

  // write CW slice: 16 elems/thread (one od row, 16 consecutive ri)
  const int od   = t >> 2;          // 0..63
  const int ril0 = (t & 3) * 16;
  const int o = od >> 5, d = od & 31;
  float* dst = CW + od * 4096 + r0 * 8 + ril0;
  #pragma unroll
  for (int q = 0; q < 16; ++q) {
    const int ril = ril0 + q;
    const int rr = ril >> 3, i = ril & 7;
    dst[q] = c_s[rr][o] * Wd[(((r0 + rr) * 2 + o) * 32 + d) * 8 + i];
  }
  // zero s slice
  f32x4* sz = (f32x4*)(s + blockIdx.x * 4096 + t * 16);
  const f32x4 z = {0.f, 0.f, 0.f, 0.f};
  sz[0] = z; sz[1] = z; sz[2] = z; sz[3] = z;
}

// ---------------------------------------------------------------------------
// SV GEMM: s[b,od] += sum_{ri in slice} u[b,ri]*CW[od,ri].
// ---------------------------------------------------------------------------
__global__ __launch_bounds__(256, 2) void sv_gemm(
    const float* __restrict__ u, const float* __restrict__ CW,
    float* __restrict__ s)
{
  __shared__ float u_s[64][68];
  __shared__ float w_s[64][68];
  const int t  = threadIdx.x;
  const int bt = blockIdx.x >> 3, ks = blockIdx.x & 7;
  const int b0 = bt * 64, k0 = ks * 512;
  const int cg = t & 15, rg = t >> 4;
  const int srow = t >> 2, scol = (t & 3) * 16;

  float acc[4][4];
  #pragma unroll
  for (int i = 0; i < 4; ++i)
    #pragma unroll
    for (int j = 0; j < 4; ++j) acc[i][j] = 0.f;

  for (int ch = 0; ch < 8; ++ch) {
    const int kb = k0 + ch * 64;
    const float* ug = u  + (b0 + srow) * 4096 + kb + scol;
    const float* wg = CW + srow * 4096 + kb + scol;
    #pragma unroll
    for (int q = 0; q < 4; ++q) {
      *(f32x4*)&u_s[srow][scol + q * 4] = *(const f32x4*)(ug + q * 4);
      *(f32x4*)&w_s[srow][scol + q * 4] = *(const f32x4*)(wg + q * 4);
    }
    __syncthreads();
    #pragma unroll 4
    for (int k4 = 0; k4 < 16; ++k4) {
      f32x4 uv[4], wv[4];
      #pragma unroll
      for (int i = 0; i < 4; ++i) uv[i] = *(const f32x4*)&u_s[rg + 16 * i][k4 * 4];
      #pragma unroll
      for (int j = 0; j < 4; ++j) wv[j] = *(const f32x4*)&w_s[cg + 16 * j][k4 * 4];
      #pragma unroll
      for (int i = 0; i < 4; ++i)
        #pragma unroll
        for (int j = 0; j < 4; ++j)
          acc[i][j] += uv[i].x * wv[j].x + uv[i].y * wv[j].y + uv[i].z * wv[j].z + uv[i].w * wv[j].w;
    }
    __syncthreads();
  }
  #pragma unroll
  for (int i = 0; i < 4; ++i)
    #pragma unroll
    for (int j = 0; j < 4; ++j)
      atomicAdd(&s[(b0 + rg + 16 * i) * 64 + cg + 16 * j], acc[i][j]);
}

// ---------------------------------------------------------------------------
// SQ kernel: v = squash(s) in-place; final: write out tuple pieces + h0;
// else zero G for the upcoming g_gemm.
// ---------------------------------------------------------------------------
__global__ __launch_bounds__(256, 2) void sq_kernel(
    float* __restrict__ s, float* __restrict__ G,
    float* __restrict__ out, float* __restrict__ h0, const int final_)
{
  const int t = threadIdx.x;
  const int b = blockIdx.x * 16 + (t >> 4);
  const int l = t & 15;
  const int o = l >> 3;
  f32x4 s4 = *(const f32x4*)&s[b * 64 + l * 4];
  float sq = s4.x * s4.x + s4.y * s4.y + s4.z * s4.z + s4.w * s4.w;
  sq += __shfl_xor(sq, 1); sq += __shfl_xor(sq, 2); sq += __shfl_xor(sq, 4);
  const float scale = sq / ((1.f + sq) * sqrtf(sq + 1e-9f));
  f32x4 v4;
  v4.x = s4.x * scale; v4.y = s4.y * scale; v4.z = s4.z * scale; v4.w = s4.w * scale;
  if (!final_) {
    *(f32x4*)&s[b * 64 + l * 4] = v4;                 // v in-place
    const f32x4 z = {0.f, 0.f, 0.f, 0.f};
    *(f32x4*)&G[blockIdx.x * 1024 + t * 4] = z;       // zero G
  } else {
    *(f32x4*)&out[b * 64 + l * 4] = v4;               // output v_j
    const float sqv = sq * scale * scale;             // ||v_o||^2
    const float sqo = __shfl_xor(sqv, 8);
    const bool win = (o == 0) ? !(sqo > sqv) : (sqv > sqo);   // np first-max
    if (l == 0 || l == 8) out[524288 + b * 2 + o] = win ? 1.f : 0.f;
    f32x4 hz = win ? v4 : f32x4{0.f, 0.f, 0.f, 0.f};
    *(f32x4*)&h0[b * 64 + l * 4] = hz;
  }
}

// ---------------------------------------------------------------------------
// G GEMM: G[od, ri] += sum_{b in slice} v[b,od]*u[b,ri].
// ---------------------------------------------------------------------------
__global__ __launch_bounds__(256, 2) void g_gemm(
    const float* __restrict__ u, const float* __restrict__ v,
    float* __restrict__ G)
{
  __shared__ float v_s[64][68];
  __shared__ float q_s[64][68];
  const int t  = threadIdx.x;
  const int rt = blockIdx.x >> 3, bs = blockIdx.x & 7;
  const int ri0 = rt * 64, b0 = bs * 512;
  const int cg = t & 15, rg = t >> 4;    // od4 = rg*4 (broadcast rows), ri4 = cg*4
  const int srow = t >> 2, scol = (t & 3) * 16;

  float acc[4][4];
  #pragma unroll
  for (int i = 0; i < 4; ++i)
    #pragma unroll
    for (int j = 0; j < 4; ++j) acc[i][j] = 0.f;

  for (int ch = 0; ch < 8; ++ch) {
    const int bb = b0 + ch * 64;
    const float* vg = v + (bb + srow) * 64 + scol;
    const float* ug = u + (bb + srow) * 4096 + ri0 + scol;
    #pragma unroll
    for (int q = 0; q < 4; ++q) {
      *(f32x4*)&v_s[srow][scol + q * 4] = *(const f32x4*)(vg + q * 4);
      *(f32x4*)&q_s[srow][scol + q * 4] = *(const f32x4*)(ug + q * 4);
    }
    __syncthreads();
    #pragma unroll 4
    for (int k = 0; k < 64; ++k) {
      const f32x4 vv = *(const f32x4*)&v_s[k][rg * 4];
      const f32x4 uu = *(const f32x4*)&q_s[k][cg * 4];
      acc[0][0] += vv.x * uu.x; acc[0][1] += vv.x * uu.y; acc[0][2] += vv.x * uu.z; acc[0][3] += vv.x * uu.w;
      acc[1][0] += vv.y * uu.x; acc[1][1] += vv.y * uu.y; acc[1][2] += vv.y * uu.z; acc[1][3] += vv.y * uu.w;
      acc[2][0] += vv.z * uu.x; acc[2][1] += vv.z * uu.y; acc[2][2] += vv.z * uu.z; acc[2][3] += vv.z * uu.w;
      acc[3][0] += vv.w * uu.x; acc[3][1] += vv.w * uu.y; acc[3][2] += vv.w * uu.z; acc[3][3] += vv.w * uu.w;
    }
    __syncthreads();
  }
  #pragma unroll
  for (int i = 0; i < 4; ++i)
    #pragma unroll
    for (int j = 0; j < 4; ++j)
      atomicAdd(&G[(rg * 4 + i) * 4096 + ri0 + cg * 4 + j], acc[i][j]);
}

// ---------------------------------------------------------------------------
// BL kernel: blog[r,o] += (1/4096) * sum_{d,i} W[r,o,d,i] * G[o*32+d, r*8+i].
// ---------------------------------------------------------------------------
__global__ __launch_bounds__(256, 2) void bl_kernel(
    const float* __restrict__ Wd, const float* __restrict__ G,
    float* __restrict__ blog)
{
  const int t = threadIdx.x;
  const int p = t >> 4, l = t & 15;
  const int r = blockIdx.x * 8 + (p >> 1), o = p & 1;
  float sum = 0.f;
  #pragma unroll
  for (int q = 0; q < 16; ++q) {
    const int idx = l * 16 + q;
    const int d = idx >> 3, i = idx & 7;
    sum += Wd[((r * 2 + o) * 32 + d) * 8 + i] * G[(o * 32 + d) * 4096 + r * 8 + i];
  }
  sum += __shfl_xor(sum, 1); sum += __shfl_xor(sum, 2);
  sum += __shfl_xor(sum, 4); sum += __shfl_xor(sum, 8);
  if (l == 0) blog[r * 2 + o] += sum * (1.f / 4096.f);
}

// ---------------------------------------------------------------------------
// K3: fused decoder (unchanged).
// ---------------------------------------------------------------------------
__global__ __launch_bounds__(256, 2) void k3_dec(
    const float* __restrict__ h0,
    const float* __restrict__ W1, const float* __restrict__ b1,
    const float* __restrict__ W2, const float* __restrict__ b2,
    const float* __restrict__ W3, const float* __restrict__ b3,
    float* __restrict__ out)
{
  __shared__ float x_s[8][64];
  __shared__ float h1_s[8][512];
  __shared__ float h2_s[8][1024];
  const int t  = threadIdx.x;
  const int b0 = blockIdx.x * 8;
  ((float*)x_s)[t]       = h0[b0 * 64 + t];
  ((float*)x_s)[t + 256] = h0[b0 * 64 + 256 + t];
  __syncthreads();
  {
    const int j = t * 2;
    float a0[8], a1[8];
    #pragma unroll
    for (int i = 0; i < 8; ++i) { a0[i] = 0.f; a1[i] = 0.f; }
    for (int k = 0; k < 64; ++k) {
      const float w0 = W1[k * 512 + j], w1 = W1[k * 512 + j + 1];
      #pragma unroll
      for (int bb = 0; bb < 8; ++bb) {
        const float x = x_s[bb][k];
        a0[bb] += w0 * x; a1[bb] += w1 * x;
      }
    }
    const float c0 = b1[j], c1 = b1[j + 1];
    #pragma unroll
    for (int bb = 0; bb < 8; ++bb) {
      h1_s[bb][j]     = fmaxf(a0[bb] + c0, 0.f);
      h1_s[bb][j + 1] = fmaxf(a1[bb] + c1, 0.f);
    }
  }
  __syncthreads();
  {
    const int j = t * 4;
    float a[4][8];
    #pragma unroll
    for (int c = 0; c < 4; ++c)
      #pragma unroll
      for (int i = 0; i < 8; ++i) a[c][i] = 0.f;
    for (int k = 0; k < 512; ++k) {
      const f32x4 w = *(const f32x4*)(W2 + k * 1024 + j);
      #pragma unroll
      for (int bb = 0; bb < 8; ++bb) {
        const float x = h1_s[bb][k];
        #pragma unroll
        for (int c = 0; c < 4; ++c) a[c][bb] += w[c] * x;
      }
    }
    #pragma unroll
    for (int c = 0; c < 4; ++c) {
      const float bc = b2[j + c];
      #pragma unroll
      for (int bb = 0; bb < 8; ++bb)
        h2_s[bb][j + c] = fmaxf(a[c][bb] + bc, 0.f);
    }
  }
  __syncthreads();
  {
    const int j = t & 63, bq = t >> 6;
    float a0 = 0.f, a1 = 0.f;
    for (int k = 0; k < 1024; ++k) {
      const float w = W3[k * 64 + j];
      a0 += w * h2_s[bq * 2][k];
      a1 += w * h2_s[bq * 2 + 1][k];
    }
    const float bc = b3[j];
    out[262144 + (b0 + bq * 2) * 64 + j]     = 1.f / (1.f + expf(-(a0 + bc)));
    out[262144 + (b0 + bq * 2 + 1) * 64 + j] = 1.f / (1.f + expf(-(a1 + bc)));
  }
}

// ---------------------------------------------------------------------------
extern "C" void kernel_launch(void* const* d_in, const int* in_sizes, int n_in,
                              void* d_out, int out_size, void* d_ws, size_t ws_size,
                              hipStream_t stream) {
  (void)in_sizes; (void)n_in; (void)out_size; (void)ws_size;
  const float* data    = (const float*)d_in[0];
  const float* conv1_w = (const float*)d_in[1];
  const float* conv1_b = (const float*)d_in[2];
  const float* prim_w  = (const float*)d_in[3];
  const float* prim_b  = (const float*)d_in[4];
  const float* Wd      = (const float*)d_in[5];
  const float* dec1_w  = (const float*)d_in[6];
  const float* dec1_b  = (const float*)d_in[7];
  const float* dec2_w  = (const float*)d_in[8];
  const float* dec2_b  = (const float*)d_in[9];
  const float* dec3_w  = (const float*)d_in[10];
  const float* dec3_b  = (const float*)d_in[11];
  char* ws = (char*)d_ws;
  unsigned short* awr_hi = (unsigned short*)ws;                    //   294912 B
  unsigned short* awr_lo = (unsigned short*)(ws + 294912);         //   294912 B
  float* blog = (float*)(ws + 589824);                             //     4096 B
  float* u    = (float*)(ws + 593920);                             // 67108864 B
  float* CW   = (float*)(ws + 593920 + 67108864);                  //  1048576 B
  float* s    = (float*)(ws + 593920 + 67108864 + 1048576);        //  1048576 B (v in-place)
  float* G    = (float*)(ws + 593920 + 67108864 + 2097152);        //  1048576 B
  float* h0   = CW;                                                //  alias: CW dead after last sv
  float* out  = (float*)d_out;

  k0_prep<<<577, 256, 0, stream>>>(prim_w, awr_hi, awr_lo, blog);
  k1_convs<<<1024, 256, 0, stream>>>(data, conv1_w, conv1_b, prim_b, awr_hi, awr_lo, u);
  // routing iteration 0 (uniform c)
  cw_kernel<<<64, 256, 0, stream>>>(blog, Wd, CW, s, 0);
  sv_gemm<<<512, 256, 0, stream>>>(u, CW, s);
  sq_kernel<<<256, 256, 0, stream>>>(s, G, out, h0, 0);
  g_gemm<<<512, 256, 0, stream>>>(u, s, G);
  bl_kernel<<<64, 256, 0, stream>>>(Wd, G, blog);
  // routing iteration 1
  cw_kernel<<<64, 256, 0, stream>>>(blog, Wd, CW, s, 1);
  sv_gemm<<<512, 256, 0, stream>>>(u, CW, s);
  sq_kernel<<<256, 256, 0, stream>>>(s, G, out, h0, 0);
  g_gemm<<<512, 256, 0, stream>>>(u, s, G);
  bl_kernel<<<64, 256, 0, stream>>>(Wd, G, blog);
  // routing iteration 2 (final)
  cw_kernel<<<64, 256, 0, stream>>>(blog, Wd, CW, s, 1);
  sv_gemm<<<512, 256, 0, stream>>>(u, CW, s);
  sq_kernel<<<256, 256, 0, stream>>>(s, G, out, h0, 1);
  // decoder
  k3_dec<<<512, 256, 0, stream>>>(h0, dec1_w, dec1_b, dec2_w, dec2_b, dec3_w, dec3_b, out);
}